// Round 2
// 476.006 us; speedup vs baseline: 1.2960x; 1.2960x over previous
//
#include <hip/hip_runtime.h>
#include <math.h>

#define NQ 512
#define NC 65536
#define DIM 768
#define PC_ROWS 128

typedef unsigned short u16;
typedef float f32x4 __attribute__((ext_vector_type(4)));
typedef short bf16x8 __attribute__((ext_vector_type(8)));

#define MFMA16(A, B, C) __builtin_amdgcn_mfma_f32_16x16x32_bf16(A, B, C, 0, 0, 0)

// ---------------------------------------------------------------------------
// bf16 helpers (RNE)
// ---------------------------------------------------------------------------
__device__ __forceinline__ u16 f2bf(float x) {
  union { float f; unsigned int u; } v; v.f = x;
  unsigned int r = v.u + 0x7fffu + ((v.u >> 16) & 1u);
  return (u16)(r >> 16);
}
__device__ __forceinline__ float bf2f(u16 h) {
  union { unsigned int u; float f; } v; v.u = ((unsigned int)h) << 16;
  return v.f;
}

// ---------------------------------------------------------------------------
// acos via A&S 4.4.46 polynomial (|err| <= 2e-8 abs)
// ---------------------------------------------------------------------------
__device__ __forceinline__ float acos_poly(float x) {
  float z = fabsf(x);
  float p = -0.0012624911f;
  p = fmaf(p, z, 0.0066700901f);
  p = fmaf(p, z, -0.0170881256f);
  p = fmaf(p, z, 0.0308918810f);
  p = fmaf(p, z, -0.0501743046f);
  p = fmaf(p, z, 0.0889789874f);
  p = fmaf(p, z, -0.2145988016f);
  p = fmaf(p, z, 1.5707963050f);
  float r = __builtin_amdgcn_sqrtf(1.0f - z) * p;
  return (x < 0.0f) ? (3.14159265358979f - r) : r;
}

// ---------------------------------------------------------------------------
// Transpose [We|Ws|Wh] into wt[768][64] (k-major) for proj_corpus s_loads.
// ---------------------------------------------------------------------------
__global__ __launch_bounds__(256) void transpose_w(
    const float* __restrict__ We, const float* __restrict__ Ws,
    const float* __restrict__ Wh, float* __restrict__ wt)
{
  int id = blockIdx.x * 256 + threadIdx.x;   // 768*64 total
  int k = id >> 6;
  int o = id & 63;
  float v = (o < 32) ? We[(size_t)o * DIM + k]
          : (o < 48) ? Ws[(size_t)(o - 32) * DIM + k]
                     : Wh[(size_t)(o - 48) * DIM + k];
  wt[id] = v;
}

// ---------------------------------------------------------------------------
// Query projection + softplus MLP weights. One block (128 thr) per query.
// Outputs:
//   qpak[q][192] bf16: [0:32) e_hi [32:64) e_lo
//                      [64:96) s_hi|s_hi dup  [96:128) s_lo|s_lo dup
//                      [128:160) h_hi|h_hi    [160:192) h_lo|h_lo
//   qmeta[q][8] f32: xn, beta, w0, w1, w2
// Duplicated K=16 segments let one 16x16x32 MFMA consume [hi|lo]-packed
// corpus operands: (r_hi|r_hi)·(s_hi|s_lo) = hi·hi + hi·lo per call.
// ---------------------------------------------------------------------------
__global__ __launch_bounds__(128) void proj_q(
    const float* __restrict__ xq,
    const float* __restrict__ We, const float* __restrict__ be,
    const float* __restrict__ Wh, const float* __restrict__ bh,
    const float* __restrict__ Ws, const float* __restrict__ bs,
    const float* __restrict__ shp,
    const float* __restrict__ W1, const float* __restrict__ b1,
    const float* __restrict__ W2, const float* __restrict__ b2,
    u16* __restrict__ qpak, float* __restrict__ qmeta)
{
  __shared__ __align__(16) float xrow[DIM];
  __shared__ float vals[96];
  __shared__ float reluv[32];
  __shared__ float hv[16];
  __shared__ float stats[8];
  const int t = threadIdx.x;
  const int q = blockIdx.x;

  for (int i = t; i < DIM; i += 128) xrow[i] = xq[(size_t)q * DIM + i];
  __syncthreads();

  if (t < 96) {
    const float* wr;
    float bias;
    if (t < 32)      { wr = We + (size_t)t * DIM;        bias = be[t]; }
    else if (t < 48) { wr = Ws + (size_t)(t - 32) * DIM; bias = bs[t - 32]; }
    else if (t < 64) { wr = Wh + (size_t)(t - 48) * DIM; bias = bh[t - 48]; }
    else             { wr = W1 + (size_t)(t - 64) * DIM; bias = b1[t - 64]; }
    const float4* x4 = (const float4*)xrow;
    const float4* w4 = (const float4*)wr;
    float acc = 0.0f;
    #pragma unroll 4
    for (int k = 0; k < DIM / 4; ++k) {
      float4 a = x4[k];
      float4 b = w4[k];
      acc = fmaf(a.x, b.x, acc);
      acc = fmaf(a.y, b.y, acc);
      acc = fmaf(a.z, b.z, acc);
      acc = fmaf(a.w, b.w, acc);
    }
    acc += bias;
    if (t >= 48 && t < 64) acc *= shp[0];
    vals[t] = acc;
  }
  __syncthreads();
  if (t < 32) reluv[t] = fmaxf(vals[64 + t], 0.0f);
  __syncthreads();

  if (t == 0) {
    float s = 0.0f;
    for (int j = 0; j < 32; ++j) s += vals[j] * vals[j];
    stats[0] = sqrtf(s);
  } else if (t == 1) {
    float s = 0.0f;
    for (int j = 32; j < 48; ++j) s += vals[j] * vals[j];
    stats[1] = sqrtf(s);
  } else if (t == 2) {
    float s = 0.0f;
    for (int j = 48; j < 64; ++j) s += vals[j] * vals[j];
    float n = fmaxf(sqrtf(s), 1e-15f);
    float f = tanhf(n) / n;
    float xn = 0.0f;
    for (int j = 0; j < 16; ++j) {
      float hj = vals[48 + j] * f;
      hv[j] = hj;
      xn += hj * hj;
    }
    stats[2] = xn;
    stats[3] = 1.0f - xn;
  } else if (t >= 3 && t < 6) {
    int m = t - 3;
    float s = 0.0f;
    for (int j = 0; j < 32; ++j) s = fmaf(reluv[j], W2[m * 32 + j], s);
    s += b2[m];
    stats[4 + m] = fmaxf(s, 0.0f) + log1pf(expf(-fabsf(s)));
  }
  __syncthreads();

  u16* qp = qpak + (size_t)q * 192;
  if (t < 32) {
    float v = vals[t] / stats[0];
    u16 hi = f2bf(v);
    u16 lo = f2bf(v - bf2f(hi));
    qp[t] = hi; qp[32 + t] = lo;
  } else if (t < 48) {
    int j = t - 32;
    float v = vals[t] / stats[1];
    u16 hi = f2bf(v);
    u16 lo = f2bf(v - bf2f(hi));
    qp[64 + j] = hi;  qp[80 + j] = hi;
    qp[96 + j] = lo;  qp[112 + j] = lo;
  } else if (t < 64) {
    int j = t - 48;
    float v = hv[j];
    u16 hi = f2bf(v);
    u16 lo = f2bf(v - bf2f(hi));
    qp[128 + j] = hi; qp[144 + j] = hi;
    qp[160 + j] = lo; qp[176 + j] = lo;
  } else if (t == 64) qmeta[(size_t)q * 8 + 0] = stats[2];
  else if (t == 65)   qmeta[(size_t)q * 8 + 1] = stats[3];
  else if (t >= 66 && t < 69) qmeta[(size_t)q * 8 + (t - 64)] = stats[4 + (t - 66)];
}

// ---------------------------------------------------------------------------
// Corpus projection: [NC,768] @ [768,64] (GEMM core unchanged).
// Epilogue emits B-fragment-ready packed bf16 hi/lo:
//   cpak[c][128]: [0:32) e_hi [32:64) e_lo [64:80) s_hi [80:96) s_lo
//                 [96:112) h_hi [112:128) h_lo
//   cyn[c] f32
// ---------------------------------------------------------------------------
__global__ __launch_bounds__(512) void proj_corpus(
    const float* __restrict__ xc, const float* __restrict__ wt,
    const float* __restrict__ be, const float* __restrict__ bh,
    const float* __restrict__ bs, const float* __restrict__ shp,
    u16* __restrict__ cpak, float* __restrict__ cyn)
{
  __shared__ float lds[8320];                 // max(32*132, 128*65) floats
  float (*lxT)[132] = (float(*)[132])lds;     // [k][row] staging
  float (*vals)[65] = (float(*)[65])lds;      // [row][out] epilogue

  const int tid = threadIdx.x;
  const int lane = tid & 63;
  const int wv = __builtin_amdgcn_readfirstlane(tid >> 6); // 0..7, uniform
  const int o0 = wv * 8;
  const int r0 = blockIdx.x * PC_ROWS;

  float acc0[8], acc1[8];
  #pragma unroll
  for (int j = 0; j < 8; ++j) { acc0[j] = 0.0f; acc1[j] = 0.0f; }

  for (int k0 = 0; k0 < DIM; k0 += 32) {
    __syncthreads();  // previous chunk's reads done before overwrite
    #pragma unroll
    for (int i = 0; i < 2; ++i) {
      int p = tid + 512 * i;          // 0..1023 = 128 rows x 8 k-quads
      int row = p >> 3;
      int kq = p & 7;
      const float4 v = *(const float4*)(xc + (size_t)(r0 + row) * DIM + k0 + 4 * kq);
      lxT[4 * kq + 0][row] = v.x;
      lxT[4 * kq + 1][row] = v.y;
      lxT[4 * kq + 2][row] = v.z;
      lxT[4 * kq + 3][row] = v.w;
    }
    __syncthreads();
    #pragma unroll
    for (int k = 0; k < 32; ++k) {
      const float xv0 = lxT[k][lane];
      const float xv1 = lxT[k][lane + 64];
      const float* wk = wt + (size_t)(k0 + k) * 64 + o0;  // uniform -> s_load
      #pragma unroll
      for (int j = 0; j < 8; ++j) {
        const float w = wk[j];
        acc0[j] = fmaf(xv0, w, acc0[j]);
        acc1[j] = fmaf(xv1, w, acc1[j]);
      }
    }
  }
  __syncthreads();

  // bias + scale_h, park raw projections
  const float sh = shp[0];
  #pragma unroll
  for (int j = 0; j < 8; ++j) {
    int o = o0 + j;
    float b = (o < 32) ? be[o] : (o < 48) ? bs[o - 32] : bh[o - 48];
    float v0 = acc0[j] + b;
    float v1 = acc1[j] + b;
    if (o >= 48) { v0 *= sh; v1 *= sh; }
    vals[lane][o] = v0;
    vals[lane + 64][o] = v1;
  }
  __syncthreads();

  const int part = tid >> 7;   // 0..3 (1 idle)
  const int row = tid & 127;
  const size_t g = (size_t)(r0 + row);
  u16* cp = cpak + g * 128;
  if (part == 0) {
    float ssum = 0.0f;
    for (int j = 0; j < 32; ++j) ssum += vals[row][j] * vals[row][j];
    float inv = 1.0f / sqrtf(ssum);
    for (int j = 0; j < 32; ++j) {
      float v = vals[row][j] * inv;
      u16 hi = f2bf(v);
      cp[j] = hi;
      cp[32 + j] = f2bf(v - bf2f(hi));
    }
  } else if (part == 1) {
    float ssum = 0.0f;
    for (int j = 32; j < 48; ++j) ssum += vals[row][j] * vals[row][j];
    float inv = 1.0f / sqrtf(ssum);
    for (int j = 0; j < 16; ++j) {
      float v = vals[row][32 + j] * inv;
      u16 hi = f2bf(v);
      cp[64 + j] = hi;
      cp[80 + j] = f2bf(v - bf2f(hi));
    }
  } else if (part == 2) {
    float ssum = 0.0f;
    for (int j = 48; j < 64; ++j) ssum += vals[row][j] * vals[row][j];
    float n = fmaxf(sqrtf(ssum), 1e-15f);
    float f = tanhf(n) / n;
    float yn = 0.0f;
    for (int j = 0; j < 16; ++j) {
      float hj = vals[row][48 + j] * f;
      u16 hi = f2bf(hj);
      cp[96 + j] = hi;
      cp[112 + j] = f2bf(hj - bf2f(hi));
      yn += hj * hj;
    }
    cyn[g] = yn;
  }
}

// ---------------------------------------------------------------------------
// Per-pair epilogue math (fast trans intrinsics; t bounded ~0.97 by geometry
// so v_rcp/v_sqrt precision (~1e-7 rel) is safe through artanh).
// ---------------------------------------------------------------------------
#define CLIPC 0.99999988f  // (float)(1.0 - 1e-7)

__device__ __forceinline__ float pair_score(
    float de, float dss, float dh,
    float xn, float beta, float w0, float w1, float w2, float yn)
{
  float dist_e = 2.0f - 2.0f * de;

  float dcl = fminf(fmaxf(dss, -CLIPC), CLIPC);
  float ac = acos_poly(dcl);
  float dist_s = ac * ac;

  float alpha = 1.0f - 2.0f * dh + yn;
  float ab = alpha * beta;
  float num = alpha * alpha * xn - 2.0f * ab * dh + beta * beta * yn;
  float den = fmaxf(1.0f - 2.0f * dh + xn * yn, 1e-15f);
  float t = __builtin_amdgcn_sqrtf(fmaxf(num, 0.0f)) * __builtin_amdgcn_rcpf(den);
  t = fminf(t, CLIPC);
  float dd = __logf((1.0f + t) * __builtin_amdgcn_rcpf(1.0f - t));
  float dist_h = dd * dd;

  return -(w0 * dist_e + w1 * dist_h + w2 * dist_s);
}

// ---------------------------------------------------------------------------
// Pairwise v3: MFMA 16x16x32_bf16, split-precision bf16 hi+lo (~fp32 dots).
// A = queries (M=q), B = corpus (N=c) -> D col=lane&15 is c (64B-segment
// coalesced stores), rows are q. Per 16q x 16c tile:
//   e (K=32):  3 MFMAs  (a_hi*b_hi + a_lo*b_hi + a_hi*b_lo)
//   s (K=16 packed [hi|lo] vs dup'd [hi|hi]/[lo|lo]): 2 MFMAs, exact product
//   h: same as s, 2 MFMAs
// Wave = 32 c (2 c-tiles, B-frags in regs) x 16 q-tiles (grid.y=2 q-halves).
// ---------------------------------------------------------------------------
__global__ __launch_bounds__(256) void pairwise(
    const u16* __restrict__ cpak, const float* __restrict__ cyn,
    const u16* __restrict__ qpak, const float* __restrict__ qmeta,
    float* __restrict__ out)
{
  const int lane = threadIdx.x & 63;
  const int wv = threadIdx.x >> 6;       // 0..3
  const int lr = lane & 15;              // A row (q) / B col (c) / D col (c)
  const int lg = lane >> 4;              // k-octet group; D row group
  const int c0 = blockIdx.x * 128 + wv * 32;
  const int qbase = blockIdx.y * 256;

  // corpus B-fragments for this wave's 32 c, all K segments
  bf16x8 Beh[2], Bel[2], Bsp[2], Bhp[2];
  float ynv[2];
  #pragma unroll
  for (int ct = 0; ct < 2; ++ct) {
    const u16* cb = cpak + (size_t)(c0 + ct * 16 + lr) * 128 + lg * 8;
    Beh[ct] = *(const bf16x8*)(cb + 0);
    Bel[ct] = *(const bf16x8*)(cb + 32);
    Bsp[ct] = *(const bf16x8*)(cb + 64);
    Bhp[ct] = *(const bf16x8*)(cb + 96);
    ynv[ct] = cyn[c0 + ct * 16 + lr];
  }

  #pragma unroll 1
  for (int qt = 0; qt < 16; ++qt) {
    const int q0 = qbase + qt * 16;
    const u16* qb = qpak + (size_t)(q0 + lr) * 192 + lg * 8;
    bf16x8 Aeh = *(const bf16x8*)(qb + 0);
    bf16x8 Ael = *(const bf16x8*)(qb + 32);
    bf16x8 Ash = *(const bf16x8*)(qb + 64);
    bf16x8 Asl = *(const bf16x8*)(qb + 96);
    bf16x8 Ahh = *(const bf16x8*)(qb + 128);
    bf16x8 Ahl = *(const bf16x8*)(qb + 160);

    // hoist per-q meta loads so their latency hides under the MFMAs
    float4 mv[4];
    float w2v[4];
    #pragma unroll
    for (int j = 0; j < 4; ++j) {
      const int q = q0 + lg * 4 + j;
      mv[j] = *(const float4*)(qmeta + (size_t)q * 8);
      w2v[j] = qmeta[(size_t)q * 8 + 4];
    }

    const f32x4 z = {0.0f, 0.0f, 0.0f, 0.0f};
    f32x4 aE[2], aS[2], aH[2];
    #pragma unroll
    for (int ct = 0; ct < 2; ++ct) {
      aE[ct] = MFMA16(Aeh, Beh[ct], z);
      aE[ct] = MFMA16(Ael, Beh[ct], aE[ct]);
      aE[ct] = MFMA16(Aeh, Bel[ct], aE[ct]);
      aS[ct] = MFMA16(Ash, Bsp[ct], z);
      aS[ct] = MFMA16(Asl, Bsp[ct], aS[ct]);
      aH[ct] = MFMA16(Ahh, Bhp[ct], z);
      aH[ct] = MFMA16(Ahl, Bhp[ct], aH[ct]);
    }

    #pragma unroll
    for (int j = 0; j < 4; ++j) {
      const int q = q0 + lg * 4 + j;
      #pragma unroll
      for (int ct = 0; ct < 2; ++ct) {
        float r = pair_score(aE[ct][j], aS[ct][j], aH[ct][j],
                             mv[j].x, mv[j].y, mv[j].z, mv[j].w, w2v[j],
                             ynv[ct]);
        out[(size_t)q * NC + c0 + ct * 16 + lr] = r;
      }
    }
  }
}

extern "C" void kernel_launch(void* const* d_in, const int* in_sizes, int n_in,
                              void* d_out, int out_size, void* d_ws, size_t ws_size,
                              hipStream_t stream) {
  const float* xq = (const float*)d_in[0];
  const float* xc = (const float*)d_in[1];
  const float* We = (const float*)d_in[2];
  const float* be = (const float*)d_in[3];
  const float* Wh = (const float*)d_in[4];
  const float* bh = (const float*)d_in[5];
  const float* Ws = (const float*)d_in[6];
  const float* bs = (const float*)d_in[7];
  const float* sh = (const float*)d_in[8];
  const float* W1 = (const float*)d_in[9];
  const float* b1 = (const float*)d_in[10];
  const float* W2 = (const float*)d_in[11];
  const float* b2 = (const float*)d_in[12];
  float* out = (float*)d_out;

  float* w = (float*)d_ws;
  u16* qpak = (u16*)w;                        // 512*192 u16 = 49152 floats
  float* qmeta = w + 49152;                   // 512*8
  float* wt = qmeta + NQ * 8;                 // 768*64
  u16* cpak = (u16*)(wt + DIM * 64);          // 65536*128 u16 = 4194304 floats
  float* cyn = (wt + DIM * 64) + 4194304;     // 65536

  transpose_w<<<DIM * 64 / 256, 256, 0, stream>>>(We, Ws, Wh, wt);
  proj_q<<<NQ, 128, 0, stream>>>(xq, We, be, Wh, bh, Ws, bs, sh, W1, b1, W2, b2,
                                 qpak, qmeta);
  proj_corpus<<<NC / PC_ROWS, 512, 0, stream>>>(xc, wt, be, bh, bs, sh, cpak, cyn);
  pairwise<<<dim3(NC / 128, 2, 1), 256, 0, stream>>>(cpak, cyn, qpak, qmeta, out);
}

// Round 3
// 445.581 us; speedup vs baseline: 1.3845x; 1.0683x over previous
//
#include <hip/hip_runtime.h>
#include <math.h>

#define NQ 512
#define NC 65536
#define DIM 768
#define PC_ROWS 128

typedef unsigned short u16;
typedef float f32x4 __attribute__((ext_vector_type(4)));
typedef short bf16x8 __attribute__((ext_vector_type(8)));

#define MFMA16(A, B, C) __builtin_amdgcn_mfma_f32_16x16x32_bf16(A, B, C, 0, 0, 0)

// ---------------------------------------------------------------------------
// bf16 helpers (RNE)
// ---------------------------------------------------------------------------
__device__ __forceinline__ u16 f2bf(float x) {
  union { float f; unsigned int u; } v; v.f = x;
  unsigned int r = v.u + 0x7fffu + ((v.u >> 16) & 1u);
  return (u16)(r >> 16);
}
__device__ __forceinline__ float bf2f(u16 h) {
  union { unsigned int u; float f; } v; v.u = ((unsigned int)h) << 16;
  return v.f;
}
__device__ __forceinline__ unsigned int pk2(u16 a, u16 b) {
  return (unsigned int)a | ((unsigned int)b << 16);
}

// ---------------------------------------------------------------------------
// acos via A&S 4.4.46 polynomial (|err| <= 2e-8 abs)
// ---------------------------------------------------------------------------
__device__ __forceinline__ float acos_poly(float x) {
  float z = fabsf(x);
  float p = -0.0012624911f;
  p = fmaf(p, z, 0.0066700901f);
  p = fmaf(p, z, -0.0170881256f);
  p = fmaf(p, z, 0.0308918810f);
  p = fmaf(p, z, -0.0501743046f);
  p = fmaf(p, z, 0.0889789874f);
  p = fmaf(p, z, -0.2145988016f);
  p = fmaf(p, z, 1.5707963050f);
  float r = __builtin_amdgcn_sqrtf(1.0f - z) * p;
  return (x < 0.0f) ? (3.14159265358979f - r) : r;
}

// ---------------------------------------------------------------------------
// Build W as MFMA B-fragments, bf16 hi/lo: wpak[kc][nt][pl][lane][8]
// (kc=24 chunks of K=32; nt=4 tiles of 16 outs; pl: 0=hi 1=lo).
// Fragment: out o = nt*16 + (lane&15), k = kc*32 + (lane>>4)*8 + j.
// Total 24*4*2*64*8 = 98304 u16 = 192 KB (L2-resident).
// ---------------------------------------------------------------------------
__global__ __launch_bounds__(256) void build_wpak(
    const float* __restrict__ We, const float* __restrict__ Ws,
    const float* __restrict__ Wh, u16* __restrict__ wpak)
{
  int id = blockIdx.x * 256 + threadIdx.x;   // 49152 = [kc][nt][lane][j]
  int j = id & 7;
  int lane = (id >> 3) & 63;
  int nt = (id >> 9) & 3;
  int kc = id >> 11;
  int o = nt * 16 + (lane & 15);
  int k = kc * 32 + ((lane >> 4) & 3) * 8 + j;
  const float* Wrow = (o < 32) ? We + (size_t)o * DIM
                    : (o < 48) ? Ws + (size_t)(o - 32) * DIM
                               : Wh + (size_t)(o - 48) * DIM;
  float w = Wrow[k];
  u16 hi = f2bf(w);
  u16 lo = f2bf(w - bf2f(hi));
  size_t base = (((size_t)kc * 4 + nt) * 2 * 64 + lane) * 8 + j;
  wpak[base] = hi;
  wpak[base + 512] = lo;   // pl=1 plane (64*8 u16 later)
}

// ---------------------------------------------------------------------------
// Query projection + softplus MLP weights. One block (128 thr) per query.
// qpak[q][192] bf16 (e hi/lo; s,h dup'd hi/lo for K=16-in-K=32 MFMA),
// qmeta[q][8] f32: xn, beta, w0, w1, w2.   (unchanged from round 2)
// ---------------------------------------------------------------------------
__global__ __launch_bounds__(128) void proj_q(
    const float* __restrict__ xq,
    const float* __restrict__ We, const float* __restrict__ be,
    const float* __restrict__ Wh, const float* __restrict__ bh,
    const float* __restrict__ Ws, const float* __restrict__ bs,
    const float* __restrict__ shp,
    const float* __restrict__ W1, const float* __restrict__ b1,
    const float* __restrict__ W2, const float* __restrict__ b2,
    u16* __restrict__ qpak, float* __restrict__ qmeta)
{
  __shared__ __align__(16) float xrow[DIM];
  __shared__ float vals[96];
  __shared__ float reluv[32];
  __shared__ float hv[16];
  __shared__ float stats[8];
  const int t = threadIdx.x;
  const int q = blockIdx.x;

  for (int i = t; i < DIM; i += 128) xrow[i] = xq[(size_t)q * DIM + i];
  __syncthreads();

  if (t < 96) {
    const float* wr;
    float bias;
    if (t < 32)      { wr = We + (size_t)t * DIM;        bias = be[t]; }
    else if (t < 48) { wr = Ws + (size_t)(t - 32) * DIM; bias = bs[t - 32]; }
    else if (t < 64) { wr = Wh + (size_t)(t - 48) * DIM; bias = bh[t - 48]; }
    else             { wr = W1 + (size_t)(t - 64) * DIM; bias = b1[t - 64]; }
    const float4* x4 = (const float4*)xrow;
    const float4* w4 = (const float4*)wr;
    float acc = 0.0f;
    #pragma unroll 4
    for (int k = 0; k < DIM / 4; ++k) {
      float4 a = x4[k];
      float4 b = w4[k];
      acc = fmaf(a.x, b.x, acc);
      acc = fmaf(a.y, b.y, acc);
      acc = fmaf(a.z, b.z, acc);
      acc = fmaf(a.w, b.w, acc);
    }
    acc += bias;
    if (t >= 48 && t < 64) acc *= shp[0];
    vals[t] = acc;
  }
  __syncthreads();
  if (t < 32) reluv[t] = fmaxf(vals[64 + t], 0.0f);
  __syncthreads();

  if (t == 0) {
    float s = 0.0f;
    for (int j = 0; j < 32; ++j) s += vals[j] * vals[j];
    stats[0] = sqrtf(s);
  } else if (t == 1) {
    float s = 0.0f;
    for (int j = 32; j < 48; ++j) s += vals[j] * vals[j];
    stats[1] = sqrtf(s);
  } else if (t == 2) {
    float s = 0.0f;
    for (int j = 48; j < 64; ++j) s += vals[j] * vals[j];
    float n = fmaxf(sqrtf(s), 1e-15f);
    float f = tanhf(n) / n;
    float xn = 0.0f;
    for (int j = 0; j < 16; ++j) {
      float hj = vals[48 + j] * f;
      hv[j] = hj;
      xn += hj * hj;
    }
    stats[2] = xn;
    stats[3] = 1.0f - xn;
  } else if (t >= 3 && t < 6) {
    int m = t - 3;
    float s = 0.0f;
    for (int j = 0; j < 32; ++j) s = fmaf(reluv[j], W2[m * 32 + j], s);
    s += b2[m];
    stats[4 + m] = fmaxf(s, 0.0f) + log1pf(expf(-fabsf(s)));
  }
  __syncthreads();

  u16* qp = qpak + (size_t)q * 192;
  if (t < 32) {
    float v = vals[t] / stats[0];
    u16 hi = f2bf(v);
    u16 lo = f2bf(v - bf2f(hi));
    qp[t] = hi; qp[32 + t] = lo;
  } else if (t < 48) {
    int j = t - 32;
    float v = vals[t] / stats[1];
    u16 hi = f2bf(v);
    u16 lo = f2bf(v - bf2f(hi));
    qp[64 + j] = hi;  qp[80 + j] = hi;
    qp[96 + j] = lo;  qp[112 + j] = lo;
  } else if (t < 64) {
    int j = t - 48;
    float v = hv[j];
    u16 hi = f2bf(v);
    u16 lo = f2bf(v - bf2f(hi));
    qp[128 + j] = hi; qp[144 + j] = hi;
    qp[160 + j] = lo; qp[176 + j] = lo;
  } else if (t == 64) qmeta[(size_t)q * 8 + 0] = stats[2];
  else if (t == 65)   qmeta[(size_t)q * 8 + 1] = stats[3];
  else if (t >= 66 && t < 69) qmeta[(size_t)q * 8 + (t - 66 + 2)] = stats[4 + (t - 66)];
}

// ---------------------------------------------------------------------------
// Corpus projection v3: MFMA 16x16x32_bf16, X split hi/lo on the fly.
// Block = 256 thr (4 waves), 128 rows. Per k-chunk (32 k):
//   stage X[128][32] as hi/lo bf16 into LDS, XOR-quad swizzle
//   (byte = row*128 + ((pl*4+lg)^(row&7))*16 + half*8) -> conflict-free
//   b64 writes and uniform-8-lanes-per-quad b128 fragment reads.
//   W fragments come straight from wpak (L1/L2). 24 MFMAs/wave/chunk.
// Epilogue: D (col=lane&15 -> out, row=(lane>>4)*4+reg) -> vals[row][65]
// in LDS (aliases staging), then normalize/pack as before.
// ---------------------------------------------------------------------------
__global__ __launch_bounds__(256) void proj_corpus(
    const float* __restrict__ xc, const u16* __restrict__ wpak,
    const float* __restrict__ be, const float* __restrict__ bh,
    const float* __restrict__ bs, const float* __restrict__ shp,
    u16* __restrict__ cpak, float* __restrict__ cyn)
{
  __shared__ float lds[8320];              // 33280 B
  u16* xpk = (u16*)lds;                    // [128 rows][128 B] staging (16 KB)
  float (*vals)[65] = (float(*)[65])lds;   // epilogue overlay (33280 B)
  __shared__ float biasc[64];
  __shared__ float shv;

  const int tid = threadIdx.x;
  const int lane = tid & 63;
  const int wv = tid >> 6;                 // 0..3
  const int lr = lane & 15;
  const int lg = lane >> 4;
  const int r0 = blockIdx.x * PC_ROWS;

  if (tid < 64) {
    biasc[tid] = (tid < 32) ? be[tid] : (tid < 48) ? bs[tid - 32] : bh[tid - 48];
    if (tid == 0) shv = shp[0];
  }

  f32x4 acc[2][4];
  #pragma unroll
  for (int rt = 0; rt < 2; ++rt)
    #pragma unroll
    for (int nt = 0; nt < 4; ++nt)
      acc[rt][nt] = (f32x4){0.0f, 0.0f, 0.0f, 0.0f};

  for (int kc = 0; kc < 24; ++kc) {
    __syncthreads();   // previous chunk's fragment reads done
    #pragma unroll
    for (int i = 0; i < 4; ++i) {
      int p = tid + 256 * i;          // 0..1023 = 128 rows x 8 k-quads
      int row = p >> 3;
      int kq = p & 7;
      const float4 v = *(const float4*)(xc + (size_t)(r0 + row) * DIM + kc * 32 + 4 * kq);
      u16 hx = f2bf(v.x), hy = f2bf(v.y), hz = f2bf(v.z), hw = f2bf(v.w);
      u16 lx = f2bf(v.x - bf2f(hx)), ly = f2bf(v.y - bf2f(hy));
      u16 lz = f2bf(v.z - bf2f(hz)), lw = f2bf(v.w - bf2f(hw));
      uint2 hvv = {pk2(hx, hy), pk2(hz, hw)};
      uint2 lvv = {pk2(lx, ly), pk2(lz, lw)};
      int rm = row & 7;
      int qh = (kq >> 1) ^ rm;          // pl=0 quad
      int ql = (4 + (kq >> 1)) ^ rm;    // pl=1 quad
      int half = (kq & 1) * 8;
      *(uint2*)((char*)xpk + row * 128 + qh * 16 + half) = hvv;
      *(uint2*)((char*)xpk + row * 128 + ql * 16 + half) = lvv;
    }
    __syncthreads();

    // W B-fragments for this chunk (all 4 out-tiles, hi+lo)
    const u16* wb = wpak + (size_t)kc * 4096;
    bf16x8 Bh[4], Bl[4];
    #pragma unroll
    for (int nt = 0; nt < 4; ++nt) {
      Bh[nt] = *(const bf16x8*)(wb + (nt * 2 + 0) * 512 + lane * 8);
      Bl[nt] = *(const bf16x8*)(wb + (nt * 2 + 1) * 512 + lane * 8);
    }

    #pragma unroll
    for (int rt = 0; rt < 2; ++rt) {
      int rowi = wv * 32 + rt * 16 + lr;
      int rm = rowi & 7;
      bf16x8 Ah = *(const bf16x8*)((const char*)xpk + rowi * 128 + (lg ^ rm) * 16);
      bf16x8 Al = *(const bf16x8*)((const char*)xpk + rowi * 128 + ((4 + lg) ^ rm) * 16);
      #pragma unroll
      for (int nt = 0; nt < 4; ++nt) {
        acc[rt][nt] = MFMA16(Ah, Bh[nt], acc[rt][nt]);
        acc[rt][nt] = MFMA16(Al, Bh[nt], acc[rt][nt]);
        acc[rt][nt] = MFMA16(Ah, Bl[nt], acc[rt][nt]);
      }
    }
  }
  __syncthreads();   // staging reads done; vals may overwrite

  #pragma unroll
  for (int rt = 0; rt < 2; ++rt)
    #pragma unroll
    for (int nt = 0; nt < 4; ++nt)
      #pragma unroll
      for (int reg = 0; reg < 4; ++reg) {
        int row = wv * 32 + rt * 16 + lg * 4 + reg;
        int o = nt * 16 + lr;
        float v = acc[rt][nt][reg] + biasc[o];
        if (o >= 48) v *= shv;
        vals[row][o] = v;
      }
  __syncthreads();

  const int part = tid >> 7;   // 0,1
  const int row = tid & 127;
  const size_t g = (size_t)(r0 + row);
  u16* cp = cpak + g * 128;
  if (part == 0) {
    float ssum = 0.0f;
    for (int j = 0; j < 32; ++j) ssum += vals[row][j] * vals[row][j];
    float inv = 1.0f / sqrtf(ssum);
    for (int j = 0; j < 32; ++j) {
      float v = vals[row][j] * inv;
      u16 hi = f2bf(v);
      cp[j] = hi;
      cp[32 + j] = f2bf(v - bf2f(hi));
    }
  } else {
    float ssum = 0.0f;
    for (int j = 32; j < 48; ++j) ssum += vals[row][j] * vals[row][j];
    float inv = 1.0f / sqrtf(ssum);
    for (int j = 0; j < 16; ++j) {
      float v = vals[row][32 + j] * inv;
      u16 hi = f2bf(v);
      cp[64 + j] = hi;
      cp[80 + j] = f2bf(v - bf2f(hi));
    }
    float hsum = 0.0f;
    for (int j = 48; j < 64; ++j) hsum += vals[row][j] * vals[row][j];
    float n = fmaxf(sqrtf(hsum), 1e-15f);
    float f = tanhf(n) / n;
    float yn = 0.0f;
    for (int j = 0; j < 16; ++j) {
      float hj = vals[row][48 + j] * f;
      u16 hi = f2bf(hj);
      cp[96 + j] = hi;
      cp[112 + j] = f2bf(hj - bf2f(hi));
      yn += hj * hj;
    }
    cyn[g] = yn;
  }
}

// ---------------------------------------------------------------------------
// Per-pair epilogue math (fast trans intrinsics).
// ---------------------------------------------------------------------------
#define CLIPC 0.99999988f  // (float)(1.0 - 1e-7)

__device__ __forceinline__ float pair_score(
    float de, float dss, float dh,
    float xn, float beta, float w0, float w1, float w2, float yn)
{
  float dist_e = 2.0f - 2.0f * de;

  float dcl = fminf(fmaxf(dss, -CLIPC), CLIPC);
  float ac = acos_poly(dcl);
  float dist_s = ac * ac;

  float alpha = 1.0f - 2.0f * dh + yn;
  float ab = alpha * beta;
  float num = alpha * alpha * xn - 2.0f * ab * dh + beta * beta * yn;
  float den = fmaxf(1.0f - 2.0f * dh + xn * yn, 1e-15f);
  float t = __builtin_amdgcn_sqrtf(fmaxf(num, 0.0f)) * __builtin_amdgcn_rcpf(den);
  t = fminf(t, CLIPC);
  float dd = __logf((1.0f + t) * __builtin_amdgcn_rcpf(1.0f - t));
  float dist_h = dd * dd;

  return -(w0 * dist_e + w1 * dist_h + w2 * dist_s);
}

// ---------------------------------------------------------------------------
// Pairwise MFMA (unchanged from round 2: 7 MFMAs per 16q x 16c tile).
// ---------------------------------------------------------------------------
__global__ __launch_bounds__(256) void pairwise(
    const u16* __restrict__ cpak, const float* __restrict__ cyn,
    const u16* __restrict__ qpak, const float* __restrict__ qmeta,
    float* __restrict__ out)
{
  const int lane = threadIdx.x & 63;
  const int wv = threadIdx.x >> 6;       // 0..3
  const int lr = lane & 15;              // A row (q) / B col (c) / D col (c)
  const int lg = lane >> 4;              // k-octet group; D row group
  const int c0 = blockIdx.x * 128 + wv * 32;
  const int qbase = blockIdx.y * 256;

  bf16x8 Beh[2], Bel[2], Bsp[2], Bhp[2];
  float ynv[2];
  #pragma unroll
  for (int ct = 0; ct < 2; ++ct) {
    const u16* cb = cpak + (size_t)(c0 + ct * 16 + lr) * 128 + lg * 8;
    Beh[ct] = *(const bf16x8*)(cb + 0);
    Bel[ct] = *(const bf16x8*)(cb + 32);
    Bsp[ct] = *(const bf16x8*)(cb + 64);
    Bhp[ct] = *(const bf16x8*)(cb + 96);
    ynv[ct] = cyn[c0 + ct * 16 + lr];
  }

  #pragma unroll 1
  for (int qt = 0; qt < 16; ++qt) {
    const int q0 = qbase + qt * 16;
    const u16* qb = qpak + (size_t)(q0 + lr) * 192 + lg * 8;
    bf16x8 Aeh = *(const bf16x8*)(qb + 0);
    bf16x8 Ael = *(const bf16x8*)(qb + 32);
    bf16x8 Ash = *(const bf16x8*)(qb + 64);
    bf16x8 Asl = *(const bf16x8*)(qb + 96);
    bf16x8 Ahh = *(const bf16x8*)(qb + 128);
    bf16x8 Ahl = *(const bf16x8*)(qb + 160);

    float4 mv[4];
    float w2v[4];
    #pragma unroll
    for (int j = 0; j < 4; ++j) {
      const int q = q0 + lg * 4 + j;
      mv[j] = *(const float4*)(qmeta + (size_t)q * 8);
      w2v[j] = qmeta[(size_t)q * 8 + 4];
    }

    const f32x4 z = {0.0f, 0.0f, 0.0f, 0.0f};
    f32x4 aE[2], aS[2], aH[2];
    #pragma unroll
    for (int ct = 0; ct < 2; ++ct) {
      aE[ct] = MFMA16(Aeh, Beh[ct], z);
      aE[ct] = MFMA16(Ael, Beh[ct], aE[ct]);
      aE[ct] = MFMA16(Aeh, Bel[ct], aE[ct]);
      aS[ct] = MFMA16(Ash, Bsp[ct], z);
      aS[ct] = MFMA16(Asl, Bsp[ct], aS[ct]);
      aH[ct] = MFMA16(Ahh, Bhp[ct], z);
      aH[ct] = MFMA16(Ahl, Bhp[ct], aH[ct]);
    }

    #pragma unroll
    for (int j = 0; j < 4; ++j) {
      const int q = q0 + lg * 4 + j;
      #pragma unroll
      for (int ct = 0; ct < 2; ++ct) {
        float r = pair_score(aE[ct][j], aS[ct][j], aH[ct][j],
                             mv[j].x, mv[j].y, mv[j].z, mv[j].w, w2v[j],
                             ynv[ct]);
        out[(size_t)q * NC + c0 + ct * 16 + lr] = r;
      }
    }
  }
}

extern "C" void kernel_launch(void* const* d_in, const int* in_sizes, int n_in,
                              void* d_out, int out_size, void* d_ws, size_t ws_size,
                              hipStream_t stream) {
  const float* xq = (const float*)d_in[0];
  const float* xc = (const float*)d_in[1];
  const float* We = (const float*)d_in[2];
  const float* be = (const float*)d_in[3];
  const float* Wh = (const float*)d_in[4];
  const float* bh = (const float*)d_in[5];
  const float* Ws = (const float*)d_in[6];
  const float* bs = (const float*)d_in[7];
  const float* sh = (const float*)d_in[8];
  const float* W1 = (const float*)d_in[9];
  const float* b1 = (const float*)d_in[10];
  const float* W2 = (const float*)d_in[11];
  const float* b2 = (const float*)d_in[12];
  float* out = (float*)d_out;

  float* w = (float*)d_ws;
  u16* qpak = (u16*)w;                        // 512*192 u16 = 49152 floats
  float* qmeta = w + 49152;                   // 512*8 = 4096 floats
  u16* wpak = (u16*)(qmeta + NQ * 8);         // 98304 u16 = 49152 floats
  float* base2 = qmeta + NQ * 8 + 49152;
  u16* cpak = (u16*)base2;                    // 65536*128 u16 = 4194304 floats
  float* cyn = base2 + 4194304;               // 65536

  build_wpak<<<192, 256, 0, stream>>>(We, Ws, Wh, wpak);
  proj_q<<<NQ, 128, 0, stream>>>(xq, We, be, Wh, bh, Ws, bs, sh, W1, b1, W2, b2,
                                 qpak, qmeta);
  proj_corpus<<<NC / PC_ROWS, 256, 0, stream>>>(xc, wpak, be, bh, bs, sh, cpak, cyn);
  pairwise<<<dim3(NC / 128, 2, 1), 256, 0, stream>>>(cpak, cyn, qpak, qmeta, out);
}

// Round 4
// 439.356 us; speedup vs baseline: 1.4041x; 1.0142x over previous
//
#include <hip/hip_runtime.h>
#include <math.h>

#define NQ 512
#define NC 65536
#define DIM 768
#define PC_ROWS 128

typedef unsigned short u16;
typedef float f32x4 __attribute__((ext_vector_type(4)));
typedef short bf16x8 __attribute__((ext_vector_type(8)));

#define MFMA16(A, B, C) __builtin_amdgcn_mfma_f32_16x16x32_bf16(A, B, C, 0, 0, 0)

// ---------------------------------------------------------------------------
// bf16 helpers (RNE)
// ---------------------------------------------------------------------------
__device__ __forceinline__ u16 f2bf(float x) {
  union { float f; unsigned int u; } v; v.f = x;
  unsigned int r = v.u + 0x7fffu + ((v.u >> 16) & 1u);
  return (u16)(r >> 16);
}
__device__ __forceinline__ float bf2f(u16 h) {
  union { unsigned int u; float f; } v; v.u = ((unsigned int)h) << 16;
  return v.f;
}
__device__ __forceinline__ unsigned int pk2(u16 a, u16 b) {
  return (unsigned int)a | ((unsigned int)b << 16);
}

// ---------------------------------------------------------------------------
// acos via A&S 4.4.46 polynomial (|err| <= 2e-8 abs)
// ---------------------------------------------------------------------------
__device__ __forceinline__ float acos_poly(float x) {
  float z = fabsf(x);
  float p = -0.0012624911f;
  p = fmaf(p, z, 0.0066700901f);
  p = fmaf(p, z, -0.0170881256f);
  p = fmaf(p, z, 0.0308918810f);
  p = fmaf(p, z, -0.0501743046f);
  p = fmaf(p, z, 0.0889789874f);
  p = fmaf(p, z, -0.2145988016f);
  p = fmaf(p, z, 1.5707963050f);
  float r = __builtin_amdgcn_sqrtf(1.0f - z) * p;
  return (x < 0.0f) ? (3.14159265358979f - r) : r;
}

// ---------------------------------------------------------------------------
// Build W as MFMA B-fragments, bf16 hi/lo: wpak[kc][nt][pl][lane][8]
// (kc=24 chunks of K=32; nt=4 tiles of 16 outs; pl: 0=hi 1=lo).
// Fragment: out o = nt*16 + (lane&15), k = kc*32 + (lane>>4)*8 + j.
// ---------------------------------------------------------------------------
__global__ __launch_bounds__(256) void build_wpak(
    const float* __restrict__ We, const float* __restrict__ Ws,
    const float* __restrict__ Wh, u16* __restrict__ wpak)
{
  int id = blockIdx.x * 256 + threadIdx.x;   // 49152 = [kc][nt][lane][j]
  int j = id & 7;
  int lane = (id >> 3) & 63;
  int nt = (id >> 9) & 3;
  int kc = id >> 11;
  int o = nt * 16 + (lane & 15);
  int k = kc * 32 + ((lane >> 4) & 3) * 8 + j;
  const float* Wrow = (o < 32) ? We + (size_t)o * DIM
                    : (o < 48) ? Ws + (size_t)(o - 32) * DIM
                               : Wh + (size_t)(o - 48) * DIM;
  float w = Wrow[k];
  u16 hi = f2bf(w);
  u16 lo = f2bf(w - bf2f(hi));
  size_t base = (((size_t)kc * 4 + nt) * 2 * 64 + lane) * 8 + j;
  wpak[base] = hi;
  wpak[base + 512] = lo;
}

// ---------------------------------------------------------------------------
// Query projection + MLP weights (unchanged).
// ---------------------------------------------------------------------------
__global__ __launch_bounds__(128) void proj_q(
    const float* __restrict__ xq,
    const float* __restrict__ We, const float* __restrict__ be,
    const float* __restrict__ Wh, const float* __restrict__ bh,
    const float* __restrict__ Ws, const float* __restrict__ bs,
    const float* __restrict__ shp,
    const float* __restrict__ W1, const float* __restrict__ b1,
    const float* __restrict__ W2, const float* __restrict__ b2,
    u16* __restrict__ qpak, float* __restrict__ qmeta)
{
  __shared__ __align__(16) float xrow[DIM];
  __shared__ float vals[96];
  __shared__ float reluv[32];
  __shared__ float hv[16];
  __shared__ float stats[8];
  const int t = threadIdx.x;
  const int q = blockIdx.x;

  for (int i = t; i < DIM; i += 128) xrow[i] = xq[(size_t)q * DIM + i];
  __syncthreads();

  if (t < 96) {
    const float* wr;
    float bias;
    if (t < 32)      { wr = We + (size_t)t * DIM;        bias = be[t]; }
    else if (t < 48) { wr = Ws + (size_t)(t - 32) * DIM; bias = bs[t - 32]; }
    else if (t < 64) { wr = Wh + (size_t)(t - 48) * DIM; bias = bh[t - 48]; }
    else             { wr = W1 + (size_t)(t - 64) * DIM; bias = b1[t - 64]; }
    const float4* x4 = (const float4*)xrow;
    const float4* w4 = (const float4*)wr;
    float acc = 0.0f;
    #pragma unroll 4
    for (int k = 0; k < DIM / 4; ++k) {
      float4 a = x4[k];
      float4 b = w4[k];
      acc = fmaf(a.x, b.x, acc);
      acc = fmaf(a.y, b.y, acc);
      acc = fmaf(a.z, b.z, acc);
      acc = fmaf(a.w, b.w, acc);
    }
    acc += bias;
    if (t >= 48 && t < 64) acc *= shp[0];
    vals[t] = acc;
  }
  __syncthreads();
  if (t < 32) reluv[t] = fmaxf(vals[64 + t], 0.0f);
  __syncthreads();

  if (t == 0) {
    float s = 0.0f;
    for (int j = 0; j < 32; ++j) s += vals[j] * vals[j];
    stats[0] = sqrtf(s);
  } else if (t == 1) {
    float s = 0.0f;
    for (int j = 32; j < 48; ++j) s += vals[j] * vals[j];
    stats[1] = sqrtf(s);
  } else if (t == 2) {
    float s = 0.0f;
    for (int j = 48; j < 64; ++j) s += vals[j] * vals[j];
    float n = fmaxf(sqrtf(s), 1e-15f);
    float f = tanhf(n) / n;
    float xn = 0.0f;
    for (int j = 0; j < 16; ++j) {
      float hj = vals[48 + j] * f;
      hv[j] = hj;
      xn += hj * hj;
    }
    stats[2] = xn;
    stats[3] = 1.0f - xn;
  } else if (t >= 3 && t < 6) {
    int m = t - 3;
    float s = 0.0f;
    for (int j = 0; j < 32; ++j) s = fmaf(reluv[j], W2[m * 32 + j], s);
    s += b2[m];
    stats[4 + m] = fmaxf(s, 0.0f) + log1pf(expf(-fabsf(s)));
  }
  __syncthreads();

  u16* qp = qpak + (size_t)q * 192;
  if (t < 32) {
    float v = vals[t] / stats[0];
    u16 hi = f2bf(v);
    u16 lo = f2bf(v - bf2f(hi));
    qp[t] = hi; qp[32 + t] = lo;
  } else if (t < 48) {
    int j = t - 32;
    float v = vals[t] / stats[1];
    u16 hi = f2bf(v);
    u16 lo = f2bf(v - bf2f(hi));
    qp[64 + j] = hi;  qp[80 + j] = hi;
    qp[96 + j] = lo;  qp[112 + j] = lo;
  } else if (t < 64) {
    int j = t - 48;
    float v = hv[j];
    u16 hi = f2bf(v);
    u16 lo = f2bf(v - bf2f(hi));
    qp[128 + j] = hi; qp[144 + j] = hi;
    qp[160 + j] = lo; qp[176 + j] = lo;
  } else if (t == 64) qmeta[(size_t)q * 8 + 0] = stats[2];
  else if (t == 65)   qmeta[(size_t)q * 8 + 1] = stats[3];
  else if (t >= 66 && t < 69) qmeta[(size_t)q * 8 + (t - 66 + 2)] = stats[4 + (t - 66)];
}

// ---------------------------------------------------------------------------
// Corpus projection v4: same MFMA/swizzle math as v3, plus T14 prefetch:
// chunk k+1's global loads are issued (into regs) right after chunk k's LDS
// writes and BEFORE the barrier; reg-destined loads stay in flight across
// s_barrier, so HBM latency hides under the 24-MFMA phase.
// ---------------------------------------------------------------------------
__global__ __launch_bounds__(256) void proj_corpus(
    const float* __restrict__ xc, const u16* __restrict__ wpak,
    const float* __restrict__ be, const float* __restrict__ bh,
    const float* __restrict__ bs, const float* __restrict__ shp,
    u16* __restrict__ cpak, float* __restrict__ cyn)
{
  __shared__ float lds[8320];              // 33280 B
  u16* xpk = (u16*)lds;                    // [128 rows][128 B] staging (16 KB)
  float (*vals)[65] = (float(*)[65])lds;   // epilogue overlay
  __shared__ float biasc[64];
  __shared__ float shv;

  const int tid = threadIdx.x;
  const int lane = tid & 63;
  const int wv = tid >> 6;                 // 0..3
  const int lr = lane & 15;
  const int lg = lane >> 4;
  const int r0 = blockIdx.x * PC_ROWS;

  if (tid < 64) {
    biasc[tid] = (tid < 32) ? be[tid] : (tid < 48) ? bs[tid - 32] : bh[tid - 48];
    if (tid == 0) shv = shp[0];
  }

  // loop-invariant per-thread staging geometry: 4 (row,kq) pairs
  const int row0 = tid >> 3,           kq0 = tid & 7;
  const int row1 = (tid + 256) >> 3,   kq1 = (tid + 256) & 7;
  const int row2 = (tid + 512) >> 3,   kq2 = (tid + 512) & 7;
  const int row3 = (tid + 768) >> 3,   kq3 = (tid + 768) & 7;
  const float* bp0 = xc + (size_t)(r0 + row0) * DIM + 4 * kq0;
  const float* bp1 = xc + (size_t)(r0 + row1) * DIM + 4 * kq1;
  const float* bp2 = xc + (size_t)(r0 + row2) * DIM + 4 * kq2;
  const float* bp3 = xc + (size_t)(r0 + row3) * DIM + 4 * kq3;

  f32x4 acc[2][4];
  #pragma unroll
  for (int rt = 0; rt < 2; ++rt)
    #pragma unroll
    for (int nt = 0; nt < 4; ++nt)
      acc[rt][nt] = (f32x4){0.0f, 0.0f, 0.0f, 0.0f};

  // prologue: chunk 0 into regs
  float4 s0 = *(const float4*)(bp0);
  float4 s1 = *(const float4*)(bp1);
  float4 s2 = *(const float4*)(bp2);
  float4 s3 = *(const float4*)(bp3);

  #pragma unroll 1
  for (int kc = 0; kc < 24; ++kc) {
    __syncthreads();   // previous chunk's fragment reads done
    // ---- convert + LDS write (same swizzle as v3) ----
    {
      const int rows[4] = {row0, row1, row2, row3};
      const int kqs[4]  = {kq0, kq1, kq2, kq3};
      float4 sv[4] = {s0, s1, s2, s3};
      #pragma unroll
      for (int i = 0; i < 4; ++i) {
        float4 v = sv[i];
        u16 hx = f2bf(v.x), hy = f2bf(v.y), hz = f2bf(v.z), hw = f2bf(v.w);
        u16 lx = f2bf(v.x - bf2f(hx)), ly = f2bf(v.y - bf2f(hy));
        u16 lz = f2bf(v.z - bf2f(hz)), lw = f2bf(v.w - bf2f(hw));
        uint2 hvv = {pk2(hx, hy), pk2(hz, hw)};
        uint2 lvv = {pk2(lx, ly), pk2(lz, lw)};
        int row = rows[i], kq = kqs[i];
        int rm = row & 7;
        int qh = (kq >> 1) ^ rm;
        int ql = (4 + (kq >> 1)) ^ rm;
        int half = (kq & 1) * 8;
        *(uint2*)((char*)xpk + row * 128 + qh * 16 + half) = hvv;
        *(uint2*)((char*)xpk + row * 128 + ql * 16 + half) = lvv;
      }
    }
    // ---- issue next chunk's loads (hide under MFMA phase) ----
    const int kn = (kc < 23) ? (kc + 1) * 32 : kc * 32;
    s0 = *(const float4*)(bp0 + kn);
    s1 = *(const float4*)(bp1 + kn);
    s2 = *(const float4*)(bp2 + kn);
    s3 = *(const float4*)(bp3 + kn);
    __syncthreads();   // staging visible

    // W B-fragments for this chunk (L1/L2-resident)
    const u16* wb = wpak + (size_t)kc * 4096;
    bf16x8 Bh[4], Bl[4];
    #pragma unroll
    for (int nt = 0; nt < 4; ++nt) {
      Bh[nt] = *(const bf16x8*)(wb + (nt * 2 + 0) * 512 + lane * 8);
      Bl[nt] = *(const bf16x8*)(wb + (nt * 2 + 1) * 512 + lane * 8);
    }

    #pragma unroll
    for (int rt = 0; rt < 2; ++rt) {
      int rowi = wv * 32 + rt * 16 + lr;
      int rm = rowi & 7;
      bf16x8 Ah = *(const bf16x8*)((const char*)xpk + rowi * 128 + (lg ^ rm) * 16);
      bf16x8 Al = *(const bf16x8*)((const char*)xpk + rowi * 128 + ((4 + lg) ^ rm) * 16);
      #pragma unroll
      for (int nt = 0; nt < 4; ++nt) {
        acc[rt][nt] = MFMA16(Ah, Bh[nt], acc[rt][nt]);
        acc[rt][nt] = MFMA16(Al, Bh[nt], acc[rt][nt]);
        acc[rt][nt] = MFMA16(Ah, Bl[nt], acc[rt][nt]);
      }
    }
  }
  __syncthreads();   // staging reads done; vals may overwrite

  #pragma unroll
  for (int rt = 0; rt < 2; ++rt)
    #pragma unroll
    for (int nt = 0; nt < 4; ++nt)
      #pragma unroll
      for (int reg = 0; reg < 4; ++reg) {
        int row = wv * 32 + rt * 16 + lg * 4 + reg;
        int o = nt * 16 + lr;
        float v = acc[rt][nt][reg] + biasc[o];
        if (o >= 48) v *= shv;
        vals[row][o] = v;
      }
  __syncthreads();

  const int part = tid >> 7;   // 0,1
  const int row = tid & 127;
  const size_t g = (size_t)(r0 + row);
  u16* cp = cpak + g * 128;
  if (part == 0) {
    float ssum = 0.0f;
    for (int j = 0; j < 32; ++j) ssum += vals[row][j] * vals[row][j];
    float inv = 1.0f / sqrtf(ssum);
    for (int j = 0; j < 32; ++j) {
      float v = vals[row][j] * inv;
      u16 hi = f2bf(v);
      cp[j] = hi;
      cp[32 + j] = f2bf(v - bf2f(hi));
    }
  } else {
    float ssum = 0.0f;
    for (int j = 32; j < 48; ++j) ssum += vals[row][j] * vals[row][j];
    float inv = 1.0f / sqrtf(ssum);
    for (int j = 0; j < 16; ++j) {
      float v = vals[row][32 + j] * inv;
      u16 hi = f2bf(v);
      cp[64 + j] = hi;
      cp[80 + j] = f2bf(v - bf2f(hi));
    }
    float hsum = 0.0f;
    for (int j = 48; j < 64; ++j) hsum += vals[row][j] * vals[row][j];
    float n = fmaxf(sqrtf(hsum), 1e-15f);
    float f = tanhf(n) / n;
    float yn = 0.0f;
    for (int j = 0; j < 16; ++j) {
      float hj = vals[row][48 + j] * f;
      u16 hi = f2bf(hj);
      cp[96 + j] = hi;
      cp[112 + j] = f2bf(hj - bf2f(hi));
      yn += hj * hj;
    }
    cyn[g] = yn;
  }
}

// ---------------------------------------------------------------------------
// Per-pair epilogue math (fast trans intrinsics).
// ---------------------------------------------------------------------------
#define CLIPC 0.99999988f  // (float)(1.0 - 1e-7)

__device__ __forceinline__ float pair_score(
    float de, float dss, float dh,
    float xn, float beta, float w0, float w1, float w2, float yn)
{
  float dist_e = 2.0f - 2.0f * de;

  float dcl = fminf(fmaxf(dss, -CLIPC), CLIPC);
  float ac = acos_poly(dcl);
  float dist_s = ac * ac;

  float alpha = 1.0f - 2.0f * dh + yn;
  float ab = alpha * beta;
  float num = alpha * alpha * xn - 2.0f * ab * dh + beta * beta * yn;
  float den = fmaxf(1.0f - 2.0f * dh + xn * yn, 1e-15f);
  float t = __builtin_amdgcn_sqrtf(fmaxf(num, 0.0f)) * __builtin_amdgcn_rcpf(den);
  t = fminf(t, CLIPC);
  float dd = __logf((1.0f + t) * __builtin_amdgcn_rcpf(1.0f - t));
  float dist_h = dd * dd;

  return -(w0 * dist_e + w1 * dist_h + w2 * dist_s);
}

// ---------------------------------------------------------------------------
// Pairwise v4: qmeta staged in LDS once per block (kills 8 VMEM/qt);
// A-fragments double-buffered in regs — qt+1's loads issue before qt's
// MFMAs+epilogue, hiding L2 latency. unroll 2 ping-pongs the buffers.
// ---------------------------------------------------------------------------
__global__ __launch_bounds__(256) void pairwise(
    const u16* __restrict__ cpak, const float* __restrict__ cyn,
    const u16* __restrict__ qpak, const float* __restrict__ qmeta,
    float* __restrict__ out)
{
  __shared__ float4 lmv[NQ];   // 8 KB: xn,beta,w0,w1
  __shared__ float lw2[NQ];    // 2 KB: w2
  const int tid = threadIdx.x;
  for (int i = tid; i < NQ; i += 256) {
    const float* m = qmeta + (size_t)i * 8;
    lmv[i] = *(const float4*)m;
    lw2[i] = m[4];
  }

  const int lane = tid & 63;
  const int wv = tid >> 6;               // 0..3
  const int lr = lane & 15;              // A row (q) / B col (c) / D col (c)
  const int lg = lane >> 4;              // k-octet group; D row group
  const int c0 = blockIdx.x * 128 + wv * 32;
  const int qbase = blockIdx.y * 256;

  bf16x8 Beh[2], Bel[2], Bsp[2], Bhp[2];
  float ynv[2];
  #pragma unroll
  for (int ct = 0; ct < 2; ++ct) {
    const u16* cb = cpak + (size_t)(c0 + ct * 16 + lr) * 128 + lg * 8;
    Beh[ct] = *(const bf16x8*)(cb + 0);
    Bel[ct] = *(const bf16x8*)(cb + 32);
    Bsp[ct] = *(const bf16x8*)(cb + 64);
    Bhp[ct] = *(const bf16x8*)(cb + 96);
    ynv[ct] = cyn[c0 + ct * 16 + lr];
  }
  __syncthreads();   // lmv/lw2 visible

  // A-fragment preload for qt=0
  const u16* qb = qpak + (size_t)(qbase + lr) * 192 + lg * 8;
  bf16x8 Aeh = *(const bf16x8*)(qb + 0);
  bf16x8 Ael = *(const bf16x8*)(qb + 32);
  bf16x8 Ash = *(const bf16x8*)(qb + 64);
  bf16x8 Asl = *(const bf16x8*)(qb + 96);
  bf16x8 Ahh = *(const bf16x8*)(qb + 128);
  bf16x8 Ahl = *(const bf16x8*)(qb + 160);

  #pragma unroll 2
  for (int qt = 0; qt < 16; ++qt) {
    const int q0 = qbase + qt * 16;

    // issue qt+1's A loads (in flight across MFMAs + epilogue)
    const int qtn = (qt < 15) ? qt + 1 : qt;
    const u16* qn = qpak + (size_t)(qbase + qtn * 16 + lr) * 192 + lg * 8;
    bf16x8 Neh = *(const bf16x8*)(qn + 0);
    bf16x8 Nel = *(const bf16x8*)(qn + 32);
    bf16x8 Nsh = *(const bf16x8*)(qn + 64);
    bf16x8 Nsl = *(const bf16x8*)(qn + 96);
    bf16x8 Nhh = *(const bf16x8*)(qn + 128);
    bf16x8 Nhl = *(const bf16x8*)(qn + 160);

    const f32x4 z = {0.0f, 0.0f, 0.0f, 0.0f};
    f32x4 aE[2], aS[2], aH[2];
    #pragma unroll
    for (int ct = 0; ct < 2; ++ct) {
      aE[ct] = MFMA16(Aeh, Beh[ct], z);
      aE[ct] = MFMA16(Ael, Beh[ct], aE[ct]);
      aE[ct] = MFMA16(Aeh, Bel[ct], aE[ct]);
      aS[ct] = MFMA16(Ash, Bsp[ct], z);
      aS[ct] = MFMA16(Asl, Bsp[ct], aS[ct]);
      aH[ct] = MFMA16(Ahh, Bhp[ct], z);
      aH[ct] = MFMA16(Ahl, Bhp[ct], aH[ct]);
    }

    #pragma unroll
    for (int j = 0; j < 4; ++j) {
      const int q = q0 + lg * 4 + j;
      const float4 m = lmv[q];
      const float w2 = lw2[q];
      #pragma unroll
      for (int ct = 0; ct < 2; ++ct) {
        float r = pair_score(aE[ct][j], aS[ct][j], aH[ct][j],
                             m.x, m.y, m.z, m.w, w2, ynv[ct]);
        out[(size_t)q * NC + c0 + ct * 16 + lr] = r;
      }
    }

    Aeh = Neh; Ael = Nel; Ash = Nsh; Asl = Nsl; Ahh = Nhh; Ahl = Nhl;
  }
}

extern "C" void kernel_launch(void* const* d_in, const int* in_sizes, int n_in,
                              void* d_out, int out_size, void* d_ws, size_t ws_size,
                              hipStream_t stream) {
  const float* xq = (const float*)d_in[0];
  const float* xc = (const float*)d_in[1];
  const float* We = (const float*)d_in[2];
  const float* be = (const float*)d_in[3];
  const float* Wh = (const float*)d_in[4];
  const float* bh = (const float*)d_in[5];
  const float* Ws = (const float*)d_in[6];
  const float* bs = (const float*)d_in[7];
  const float* sh = (const float*)d_in[8];
  const float* W1 = (const float*)d_in[9];
  const float* b1 = (const float*)d_in[10];
  const float* W2 = (const float*)d_in[11];
  const float* b2 = (const float*)d_in[12];
  float* out = (float*)d_out;

  float* w = (float*)d_ws;
  u16* qpak = (u16*)w;                        // 512*192 u16 = 49152 floats
  float* qmeta = w + 49152;                   // 512*8 = 4096 floats
  u16* wpak = (u16*)(qmeta + NQ * 8);         // 98304 u16 = 49152 floats
  float* base2 = qmeta + NQ * 8 + 49152;
  u16* cpak = (u16*)base2;                    // 65536*128 u16 = 4194304 floats
  float* cyn = base2 + 4194304;               // 65536

  build_wpak<<<192, 256, 0, stream>>>(We, Ws, Wh, wpak);
  proj_q<<<NQ, 128, 0, stream>>>(xq, We, be, Wh, bh, Ws, bs, sh, W1, b1, W2, b2,
                                 qpak, qmeta);
  proj_corpus<<<NC / PC_ROWS, 256, 0, stream>>>(xc, wpak, be, bh, bs, sh, cpak, cyn);
  pairwise<<<dim3(NC / 128, 2, 1), 256, 0, stream>>>(cpak, cyn, qpak, qmeta, out);
}

// Round 5
// 424.651 us; speedup vs baseline: 1.4527x; 1.0346x over previous
//
#include <hip/hip_runtime.h>
#include <math.h>

#define NQ 512
#define NC 65536
#define DIM 768
#define PC_ROWS 128

typedef unsigned short u16;
typedef unsigned int u32;
typedef float f32x4 __attribute__((ext_vector_type(4)));
typedef short bf16x8 __attribute__((ext_vector_type(8)));

#define MFMA16(A, B, C) __builtin_amdgcn_mfma_f32_16x16x32_bf16(A, B, C, 0, 0, 0)

// ---------------------------------------------------------------------------
// bf16 helpers (RNE)
// ---------------------------------------------------------------------------
__device__ __forceinline__ u16 f2bf(float x) {
  union { float f; u32 u; } v; v.f = x;
  u32 r = v.u + 0x7fffu + ((v.u >> 16) & 1u);
  return (u16)(r >> 16);
}
__device__ __forceinline__ float bf2f(u16 h) {
  union { u32 u; float f; } v; v.u = ((u32)h) << 16;
  return v.f;
}
__device__ __forceinline__ float u2f(u32 u) {
  union { u32 u; float f; } v; v.u = u;
  return v.f;
}

// pack 2 f32 -> 2 bf16 in one instr (rounding mode irrelevant for hi/lo sum)
__device__ __forceinline__ u32 cvtpk(float a, float b) {
  u32 r;
  asm("v_cvt_pk_bf16_f32 %0, %1, %2" : "=v"(r) : "v"(a), "v"(b));
  return r;
}

// ---------------------------------------------------------------------------
// acos via A&S 4.4.46 polynomial (|err| <= 2e-8 abs)
// ---------------------------------------------------------------------------
__device__ __forceinline__ float acos_poly(float x) {
  float z = fabsf(x);
  float p = -0.0012624911f;
  p = fmaf(p, z, 0.0066700901f);
  p = fmaf(p, z, -0.0170881256f);
  p = fmaf(p, z, 0.0308918810f);
  p = fmaf(p, z, -0.0501743046f);
  p = fmaf(p, z, 0.0889789874f);
  p = fmaf(p, z, -0.2145988016f);
  p = fmaf(p, z, 1.5707963050f);
  float r = __builtin_amdgcn_sqrtf(1.0f - z) * p;
  return (x < 0.0f) ? (3.14159265358979f - r) : r;
}

// ---------------------------------------------------------------------------
// Build W as MFMA B-fragments, bf16 hi/lo: wpak[kc][nt][pl][lane][8]
// ---------------------------------------------------------------------------
__global__ __launch_bounds__(256) void build_wpak(
    const float* __restrict__ We, const float* __restrict__ Ws,
    const float* __restrict__ Wh, u16* __restrict__ wpak)
{
  int id = blockIdx.x * 256 + threadIdx.x;   // 49152 = [kc][nt][lane][j]
  int j = id & 7;
  int lane = (id >> 3) & 63;
  int nt = (id >> 9) & 3;
  int kc = id >> 11;
  int o = nt * 16 + (lane & 15);
  int k = kc * 32 + ((lane >> 4) & 3) * 8 + j;
  const float* Wrow = (o < 32) ? We + (size_t)o * DIM
                    : (o < 48) ? Ws + (size_t)(o - 32) * DIM
                               : Wh + (size_t)(o - 48) * DIM;
  float w = Wrow[k];
  u16 hi = f2bf(w);
  u16 lo = f2bf(w - bf2f(hi));
  size_t base = (((size_t)kc * 4 + nt) * 2 * 64 + lane) * 8 + j;
  wpak[base] = hi;
  wpak[base + 512] = lo;
}

// ---------------------------------------------------------------------------
// Query projection + MLP weights. qmeta[q][8] now holds folded constants:
//   {xn, beta^2, -2(1+xn), -2w0, 2w0, w1, w2, 0}
// ---------------------------------------------------------------------------
__global__ __launch_bounds__(128) void proj_q(
    const float* __restrict__ xq,
    const float* __restrict__ We, const float* __restrict__ be,
    const float* __restrict__ Wh, const float* __restrict__ bh,
    const float* __restrict__ Ws, const float* __restrict__ bs,
    const float* __restrict__ shp,
    const float* __restrict__ W1, const float* __restrict__ b1,
    const float* __restrict__ W2, const float* __restrict__ b2,
    u16* __restrict__ qpak, float* __restrict__ qmeta)
{
  __shared__ __align__(16) float xrow[DIM];
  __shared__ float vals[96];
  __shared__ float reluv[32];
  __shared__ float hv[16];
  __shared__ float stats[8];
  const int t = threadIdx.x;
  const int q = blockIdx.x;

  for (int i = t; i < DIM; i += 128) xrow[i] = xq[(size_t)q * DIM + i];
  __syncthreads();

  if (t < 96) {
    const float* wr;
    float bias;
    if (t < 32)      { wr = We + (size_t)t * DIM;        bias = be[t]; }
    else if (t < 48) { wr = Ws + (size_t)(t - 32) * DIM; bias = bs[t - 32]; }
    else if (t < 64) { wr = Wh + (size_t)(t - 48) * DIM; bias = bh[t - 48]; }
    else             { wr = W1 + (size_t)(t - 64) * DIM; bias = b1[t - 64]; }
    const float4* x4 = (const float4*)xrow;
    const float4* w4 = (const float4*)wr;
    float acc = 0.0f;
    #pragma unroll 4
    for (int k = 0; k < DIM / 4; ++k) {
      float4 a = x4[k];
      float4 b = w4[k];
      acc = fmaf(a.x, b.x, acc);
      acc = fmaf(a.y, b.y, acc);
      acc = fmaf(a.z, b.z, acc);
      acc = fmaf(a.w, b.w, acc);
    }
    acc += bias;
    if (t >= 48 && t < 64) acc *= shp[0];
    vals[t] = acc;
  }
  __syncthreads();
  if (t < 32) reluv[t] = fmaxf(vals[64 + t], 0.0f);
  __syncthreads();

  if (t == 0) {
    float s = 0.0f;
    for (int j = 0; j < 32; ++j) s += vals[j] * vals[j];
    stats[0] = sqrtf(s);
  } else if (t == 1) {
    float s = 0.0f;
    for (int j = 32; j < 48; ++j) s += vals[j] * vals[j];
    stats[1] = sqrtf(s);
  } else if (t == 2) {
    float s = 0.0f;
    for (int j = 48; j < 64; ++j) s += vals[j] * vals[j];
    float n = fmaxf(sqrtf(s), 1e-15f);
    float f = tanhf(n) / n;
    float xn = 0.0f;
    for (int j = 0; j < 16; ++j) {
      float hj = vals[48 + j] * f;
      hv[j] = hj;
      xn += hj * hj;
    }
    stats[2] = xn;
    stats[3] = 1.0f - xn;
  } else if (t >= 3 && t < 6) {
    int m = t - 3;
    float s = 0.0f;
    for (int j = 0; j < 32; ++j) s = fmaf(reluv[j], W2[m * 32 + j], s);
    s += b2[m];
    stats[4 + m] = fmaxf(s, 0.0f) + log1pf(expf(-fabsf(s)));
  }
  __syncthreads();

  u16* qp = qpak + (size_t)q * 192;
  if (t < 32) {
    float v = vals[t] / stats[0];
    u16 hi = f2bf(v);
    u16 lo = f2bf(v - bf2f(hi));
    qp[t] = hi; qp[32 + t] = lo;
  } else if (t < 48) {
    int j = t - 32;
    float v = vals[t] / stats[1];
    u16 hi = f2bf(v);
    u16 lo = f2bf(v - bf2f(hi));
    qp[64 + j] = hi;  qp[80 + j] = hi;
    qp[96 + j] = lo;  qp[112 + j] = lo;
  } else if (t < 64) {
    int j = t - 48;
    float v = hv[j];
    u16 hi = f2bf(v);
    u16 lo = f2bf(v - bf2f(hi));
    qp[128 + j] = hi; qp[144 + j] = hi;
    qp[160 + j] = lo; qp[176 + j] = lo;
  } else if (t == 64) {
    float xnv = stats[2];
    float bet = stats[3];
    float w0 = stats[4], w1v = stats[5], w2v = stats[6];
    float* m = qmeta + (size_t)q * 8;
    m[0] = xnv;
    m[1] = bet * bet;
    m[2] = -2.0f * (1.0f + xnv);
    m[3] = -2.0f * w0;
    m[4] = 2.0f * w0;
    m[5] = w1v;
    m[6] = w2v;
    m[7] = 0.0f;
  }
}

// ---------------------------------------------------------------------------
// Corpus projection v5: barrier-free async K-loop.
// Staging is WAVE-PRIVATE (each wave reads only its own 32 rows), f32 via
// global_load_lds (16B), double-buffered 2x4KB per wave, quad-swizzle applied
// to the GLOBAL source address (linear LDS dest): slot(row,qs) holds global
// quad qs^(row&7). No __syncthreads in the K-loop -- only per-wave counted
// s_waitcnt vmcnt(4) (chunk kc's 4 loads done; kc+1's 4 stay in flight for a
// full chunk period). f32->bf16 hi/lo conversion in-reg via v_cvt_pk_bf16_f32.
// ---------------------------------------------------------------------------
__global__ __launch_bounds__(256) void proj_corpus(
    const float* __restrict__ xc, const u16* __restrict__ wpak,
    const float* __restrict__ be, const float* __restrict__ bh,
    const float* __restrict__ bs, const float* __restrict__ shp,
    u16* __restrict__ cpak, float* __restrict__ cyn)
{
  __shared__ __align__(16) char smem[33280];   // staging 32KB, then vals overlay
  float (*vals)[65] = (float(*)[65])smem;
  __shared__ float biasc[64];
  __shared__ float shv;

  const int tid = threadIdx.x;
  const int lane = tid & 63;
  const int wv = __builtin_amdgcn_readfirstlane(tid >> 6);  // 0..3 uniform
  const int lr = lane & 15;
  const int lg = lane >> 4;
  const int r0 = blockIdx.x * PC_ROWS;

  if (tid < 64) {
    biasc[tid] = (tid < 32) ? be[tid] : (tid < 48) ? bs[tid - 32] : bh[tid - 48];
    if (tid == 0) shv = shp[0];
  }

  // global sources for the 4 gld_lds per chunk (pre-swizzled quad):
  // lane writes LDS slot (row = i*8 + lane/8, qs = lane&7) which must hold
  // global quad qg = qs ^ (row&7); row&7 == lane/8 here.
  const int row_w = lane >> 3;                 // 0..7
  const int qg = (lane & 7) ^ row_w;
  const float* g0 = xc + (size_t)(r0 + wv * 32 +  0 + row_w) * DIM + qg * 4;
  const float* g1 = xc + (size_t)(r0 + wv * 32 +  8 + row_w) * DIM + qg * 4;
  const float* g2 = xc + (size_t)(r0 + wv * 32 + 16 + row_w) * DIM + qg * 4;
  const float* g3 = xc + (size_t)(r0 + wv * 32 + 24 + row_w) * DIM + qg * 4;
  char* sbase = smem + wv * 8192;              // wave-private 2 x 4KB

#define STAGE(B, KC) do {                                                     \
    char* d_ = sbase + (B) * 4096;                                            \
    __builtin_amdgcn_global_load_lds(g0 + (KC) * 32, (void*)(d_       ), 16, 0, 0); \
    __builtin_amdgcn_global_load_lds(g1 + (KC) * 32, (void*)(d_ + 1024), 16, 0, 0); \
    __builtin_amdgcn_global_load_lds(g2 + (KC) * 32, (void*)(d_ + 2048), 16, 0, 0); \
    __builtin_amdgcn_global_load_lds(g3 + (KC) * 32, (void*)(d_ + 3072), 16, 0, 0); \
  } while (0)

  f32x4 acc[2][4];
  #pragma unroll
  for (int rt = 0; rt < 2; ++rt)
    #pragma unroll
    for (int nt = 0; nt < 4; ++nt)
      acc[rt][nt] = (f32x4){0.0f, 0.0f, 0.0f, 0.0f};

  STAGE(0, 0);

  #pragma unroll 1
  for (int kc = 0; kc < 24; ++kc) {
    const int b = kc & 1;

    // W B-fragments (L2-resident; latency folded into the vmcnt wait below)
    const u16* wb = wpak + (size_t)kc * 4096;
    bf16x8 Bh[4], Bl[4];
    #pragma unroll
    for (int nt = 0; nt < 4; ++nt) {
      Bh[nt] = *(const bf16x8*)(wb + (nt * 2 + 0) * 512 + lane * 8);
      Bl[nt] = *(const bf16x8*)(wb + (nt * 2 + 1) * 512 + lane * 8);
    }

    if (kc < 23) {
      STAGE(b ^ 1, kc + 1);
      asm volatile("s_waitcnt vmcnt(4)" ::: "memory");  // chunk kc landed
    } else {
      asm volatile("s_waitcnt vmcnt(0)" ::: "memory");
    }

    #pragma unroll
    for (int rt = 0; rt < 2; ++rt) {
      const int rwl = rt * 16 + lr;            // wave-row 0..31
      const int rm = rwl & 7;
      const char* rb = sbase + b * 4096 + rwl * 128;
      const int q0s = (2 * lg) ^ rm;
      f32x4 a0 = *(const f32x4*)(rb + q0s * 16);         // k = 8lg .. 8lg+3
      f32x4 a1 = *(const f32x4*)(rb + (q0s ^ 1) * 16);   // k = 8lg+4 .. 8lg+7

      u32 h0 = cvtpk(a0.x, a0.y);
      u32 h1 = cvtpk(a0.z, a0.w);
      u32 h2 = cvtpk(a1.x, a1.y);
      u32 h3 = cvtpk(a1.z, a1.w);
      u32 l0 = cvtpk(a0.x - u2f(h0 << 16), a0.y - u2f(h0 & 0xffff0000u));
      u32 l1 = cvtpk(a0.z - u2f(h1 << 16), a0.w - u2f(h1 & 0xffff0000u));
      u32 l2 = cvtpk(a1.x - u2f(h2 << 16), a1.y - u2f(h2 & 0xffff0000u));
      u32 l3 = cvtpk(a1.z - u2f(h3 << 16), a1.w - u2f(h3 & 0xffff0000u));
      union { u32 u[4]; bf16x8 v; } Ah, Al;
      Ah.u[0] = h0; Ah.u[1] = h1; Ah.u[2] = h2; Ah.u[3] = h3;
      Al.u[0] = l0; Al.u[1] = l1; Al.u[2] = l2; Al.u[3] = l3;

      #pragma unroll
      for (int nt = 0; nt < 4; ++nt) {
        acc[rt][nt] = MFMA16(Ah.v, Bh[nt], acc[rt][nt]);
        acc[rt][nt] = MFMA16(Al.v, Bh[nt], acc[rt][nt]);
        acc[rt][nt] = MFMA16(Ah.v, Bl[nt], acc[rt][nt]);
      }
    }
  }
#undef STAGE

  __syncthreads();   // all waves done with staging; vals overlay safe

  #pragma unroll
  for (int rt = 0; rt < 2; ++rt)
    #pragma unroll
    for (int nt = 0; nt < 4; ++nt)
      #pragma unroll
      for (int reg = 0; reg < 4; ++reg) {
        int row = wv * 32 + rt * 16 + lg * 4 + reg;
        int o = nt * 16 + lr;
        float v = acc[rt][nt][reg] + biasc[o];
        if (o >= 48) v *= shv;
        vals[row][o] = v;
      }
  __syncthreads();

  const int part = tid >> 7;   // 0,1
  const int row = tid & 127;
  const size_t g = (size_t)(r0 + row);
  u16* cp = cpak + g * 128;
  if (part == 0) {
    float ssum = 0.0f;
    for (int j = 0; j < 32; ++j) ssum += vals[row][j] * vals[row][j];
    float inv = 1.0f / sqrtf(ssum);
    for (int j = 0; j < 32; ++j) {
      float v = vals[row][j] * inv;
      u16 hi = f2bf(v);
      cp[j] = hi;
      cp[32 + j] = f2bf(v - bf2f(hi));
    }
  } else {
    float ssum = 0.0f;
    for (int j = 32; j < 48; ++j) ssum += vals[row][j] * vals[row][j];
    float inv = 1.0f / sqrtf(ssum);
    for (int j = 0; j < 16; ++j) {
      float v = vals[row][32 + j] * inv;
      u16 hi = f2bf(v);
      cp[64 + j] = hi;
      cp[80 + j] = f2bf(v - bf2f(hi));
    }
    float hsum = 0.0f;
    for (int j = 48; j < 64; ++j) hsum += vals[row][j] * vals[row][j];
    float n = fmaxf(sqrtf(hsum), 1e-15f);
    float f = tanhf(n) / n;
    float yn = 0.0f;
    for (int j = 0; j < 16; ++j) {
      float hj = vals[row][48 + j] * f;
      u16 hi = f2bf(hj);
      cp[96 + j] = hi;
      cp[112 + j] = f2bf(hj - bf2f(hi));
      yn += hj * hj;
    }
    cyn[g] = yn;
  }
}

// ---------------------------------------------------------------------------
// Pairwise epilogue, algebraically flattened:
//   num = 4u^2 - 2(1+xn)(1+yn)u + xn(1+yn)^2 + beta^2*yn   (u = <qh,ch>)
//   den = (1 + xn*yn) - 2u ;  (1+t)/(1-t) = (den+s)/(den-s), s = min(sqrt(num),
//   CLIPC*den)  -> one rcp saved, clip semantics preserved (den > 0 always).
//   mA = {xn, beta^2, -2(1+xn), -2w0};  mB = {2w0, w1, w2, -}
// ---------------------------------------------------------------------------
#define CLIPC 0.99999988f  // (float)(1.0 - 1e-7)

__device__ __forceinline__ float pair_score(
    float de, float dss, float u,
    float4 mA, float4 mB, float yn, float yp1, float yp2)
{
  float eterm = fmaf(de, mA.w, mB.x);                 // w0*(2-2de)

  float dcl = fminf(fmaxf(dss, -CLIPC), CLIPC);
  float ac = acos_poly(dcl);
  float sterm = mB.z * ac * ac;

  float Pm  = mA.z * yp1;                             // -2(1+xn)(1+yn)
  float t1  = fmaf(4.0f, u, Pm);
  float C   = fmaf(mA.x, yp2, mA.y * yn);
  float num = fmaf(u, t1, C);
  float den = fmaf(-2.0f, u, fmaf(mA.x, yn, 1.0f));
  float s = __builtin_amdgcn_sqrtf(fmaxf(num, 0.0f));
  s = fminf(s, CLIPC * den);
  float dd = __logf((den + s) * __builtin_amdgcn_rcpf(den - s));
  float hterm = mB.y * dd * dd;

  return -(eterm + hterm + sterm);
}

// ---------------------------------------------------------------------------
// Pairwise v5: MFMA dots (unchanged), folded-constant epilogue, qmeta in LDS,
// A-fragments double-buffered, nontemporal out stores (134MB never re-read).
// ---------------------------------------------------------------------------
__global__ __launch_bounds__(256) void pairwise(
    const u16* __restrict__ cpak, const float* __restrict__ cyn,
    const u16* __restrict__ qpak, const float* __restrict__ qmeta,
    float* __restrict__ out)
{
  __shared__ float4 lmA[NQ];   // xn, beta^2, -2(1+xn), -2w0
  __shared__ float4 lmB[NQ];   // 2w0, w1, w2, pad
  const int tid = threadIdx.x;
  for (int i = tid; i < NQ; i += 256) {
    const float4* m = (const float4*)(qmeta + (size_t)i * 8);
    lmA[i] = m[0];
    lmB[i] = m[1];
  }

  const int lane = tid & 63;
  const int wv = tid >> 6;               // 0..3
  const int lr = lane & 15;              // A row (q) / B col (c) / D col (c)
  const int lg = lane >> 4;              // k-octet group; D row group
  const int c0 = blockIdx.x * 128 + wv * 32;
  const int qbase = blockIdx.y * 256;

  bf16x8 Beh[2], Bel[2], Bsp[2], Bhp[2];
  float ynv[2], yp1v[2], yp2v[2];
  #pragma unroll
  for (int ct = 0; ct < 2; ++ct) {
    const u16* cb = cpak + (size_t)(c0 + ct * 16 + lr) * 128 + lg * 8;
    Beh[ct] = *(const bf16x8*)(cb + 0);
    Bel[ct] = *(const bf16x8*)(cb + 32);
    Bsp[ct] = *(const bf16x8*)(cb + 64);
    Bhp[ct] = *(const bf16x8*)(cb + 96);
    float yn = cyn[c0 + ct * 16 + lr];
    ynv[ct] = yn;
    yp1v[ct] = 1.0f + yn;
    yp2v[ct] = yp1v[ct] * yp1v[ct];
  }
  __syncthreads();   // lmA/lmB visible

  // A-fragment preload for qt=0
  const u16* qb = qpak + (size_t)(qbase + lr) * 192 + lg * 8;
  bf16x8 Aeh = *(const bf16x8*)(qb + 0);
  bf16x8 Ael = *(const bf16x8*)(qb + 32);
  bf16x8 Ash = *(const bf16x8*)(qb + 64);
  bf16x8 Asl = *(const bf16x8*)(qb + 96);
  bf16x8 Ahh = *(const bf16x8*)(qb + 128);
  bf16x8 Ahl = *(const bf16x8*)(qb + 160);

  #pragma unroll 2
  for (int qt = 0; qt < 16; ++qt) {
    const int q0 = qbase + qt * 16;

    const int qtn = (qt < 15) ? qt + 1 : qt;
    const u16* qn = qpak + (size_t)(qbase + qtn * 16 + lr) * 192 + lg * 8;
    bf16x8 Neh = *(const bf16x8*)(qn + 0);
    bf16x8 Nel = *(const bf16x8*)(qn + 32);
    bf16x8 Nsh = *(const bf16x8*)(qn + 64);
    bf16x8 Nsl = *(const bf16x8*)(qn + 96);
    bf16x8 Nhh = *(const bf16x8*)(qn + 128);
    bf16x8 Nhl = *(const bf16x8*)(qn + 160);

    const f32x4 z = {0.0f, 0.0f, 0.0f, 0.0f};
    f32x4 aE[2], aS[2], aH[2];
    #pragma unroll
    for (int ct = 0; ct < 2; ++ct) {
      aE[ct] = MFMA16(Aeh, Beh[ct], z);
      aE[ct] = MFMA16(Ael, Beh[ct], aE[ct]);
      aE[ct] = MFMA16(Aeh, Bel[ct], aE[ct]);
      aS[ct] = MFMA16(Ash, Bsp[ct], z);
      aS[ct] = MFMA16(Asl, Bsp[ct], aS[ct]);
      aH[ct] = MFMA16(Ahh, Bhp[ct], z);
      aH[ct] = MFMA16(Ahl, Bhp[ct], aH[ct]);
    }

    #pragma unroll
    for (int j = 0; j < 4; ++j) {
      const int q = q0 + lg * 4 + j;
      const float4 mA = lmA[q];
      const float4 mB = lmB[q];
      #pragma unroll
      for (int ct = 0; ct < 2; ++ct) {
        float r = pair_score(aE[ct][j], aS[ct][j], aH[ct][j],
                             mA, mB, ynv[ct], yp1v[ct], yp2v[ct]);
        __builtin_nontemporal_store(r, &out[(size_t)q * NC + c0 + ct * 16 + lr]);
      }
    }

    Aeh = Neh; Ael = Nel; Ash = Nsh; Asl = Nsl; Ahh = Nhh; Ahl = Nhl;
  }
}

extern "C" void kernel_launch(void* const* d_in, const int* in_sizes, int n_in,
                              void* d_out, int out_size, void* d_ws, size_t ws_size,
                              hipStream_t stream) {
  const float* xq = (const float*)d_in[0];
  const float* xc = (const float*)d_in[1];
  const float* We = (const float*)d_in[2];
  const float* be = (const float*)d_in[3];
  const float* Wh = (const float*)d_in[4];
  const float* bh = (const float*)d_in[5];
  const float* Ws = (const float*)d_in[6];
  const float* bs = (const float*)d_in[7];
  const float* sh = (const float*)d_in[8];
  const float* W1 = (const float*)d_in[9];
  const float* b1 = (const float*)d_in[10];
  const float* W2 = (const float*)d_in[11];
  const float* b2 = (const float*)d_in[12];
  float* out = (float*)d_out;

  float* w = (float*)d_ws;
  u16* qpak = (u16*)w;                        // 512*192 u16 = 49152 floats
  float* qmeta = w + 49152;                   // 512*8 = 4096 floats
  u16* wpak = (u16*)(qmeta + NQ * 8);         // 98304 u16 = 49152 floats
  float* base2 = qmeta + NQ * 8 + 49152;
  u16* cpak = (u16*)base2;                    // 65536*128 u16 = 4194304 floats
  float* cyn = base2 + 4194304;               // 65536

  build_wpak<<<192, 256, 0, stream>>>(We, Ws, Wh, wpak);
  proj_q<<<NQ, 128, 0, stream>>>(xq, We, be, Wh, bh, Ws, bs, sh, W1, b1, W2, b2,
                                 qpak, qmeta);
  proj_corpus<<<NC / PC_ROWS, 256, 0, stream>>>(xc, wpak, be, bh, bs, sh, cpak, cyn);
  pairwise<<<dim3(NC / 128, 2, 1), 256, 0, stream>>>(cpak, cyn, qpak, qmeta, out);
}